// Round 12
// baseline (783.277 us; speedup 1.0000x reference)
//
#include <hip/hip_runtime.h>
#include <stdint.h>

#define DEVI __device__ __forceinline__

typedef __attribute__((ext_vector_type(8))) short bf16x8;
typedef __attribute__((ext_vector_type(4))) float f32x4;
typedef __attribute__((ext_vector_type(4))) unsigned short us4;
typedef unsigned short u16;

constexpr int B_ = 4, S_ = 5, H_ = 4, C_ = 1024, D_ = 256;
constexpr int LQ = 4096, LK = 400, LKP = 448;

DEVI u16 f2b(float f){
  uint32_t x = __float_as_uint(f);
  uint32_t r = (x + 0x7FFFu + ((x >> 16) & 1u)) >> 16;
  return (u16)r;
}

typedef __attribute__((address_space(1))) const void ASG;
typedef __attribute__((address_space(3))) void ASL;
DEVI void gload16(const void* g, void* l){
  __builtin_amdgcn_global_load_lds((ASG*)g, (ASL*)l, 16, 0, 0);
}

// ---------------- fp32 -> bf16 convert ----------------
__global__ __launch_bounds__(256) void k_cvt(const float* __restrict__ s, u16* __restrict__ d, int n4){
  int i = blockIdx.x*256 + threadIdx.x;
  if (i >= n4) return;
  float4 v = ((const float4*)s)[i];
  us4 o; o.x = f2b(v.x); o.y = f2b(v.y); o.z = f2b(v.z); o.w = f2b(v.w);
  *(us4*)(d + (size_t)i*4) = o;
}

// ---------------- base_feat [B][C][LQ] -> Xb bf16 [B][LQ][C] ----------------
__global__ __launch_bounds__(256) void k_transpose_x(const float* __restrict__ base, u16* __restrict__ Xb){
  __shared__ float t[32][33];
  int l0 = blockIdx.x*32, c0 = blockIdx.y*32, b = blockIdx.z;
  int tx = threadIdx.x & 31, ty = threadIdx.x >> 5;
  const float* src = base + ((size_t)b*C_ + c0)*LQ + l0;
  #pragma unroll
  for (int i=0;i<4;i++){ int cc = ty + i*8; t[cc][tx] = src[(size_t)cc*LQ + tx]; }
  __syncthreads();
  u16* dst = Xb + ((size_t)b*LQ + l0)*C_ + c0;
  #pragma unroll
  for (int i=0;i<4;i++){ int ll = ty + i*8; dst[(size_t)ll*C_ + tx] = f2b(t[tx][ll]); }
}

// ---------------- support + pe -> smat [S][B][448][C] (rows 400..447 zero) ----------------
__global__ __launch_bounds__(256) void k_build_smat(const float* __restrict__ sup, u16* __restrict__ kc){
  __shared__ float t[32][33];
  int p0 = blockIdx.x*32, c0 = blockIdx.y*32;
  int s = blockIdx.z / B_, b = blockIdx.z % B_;
  int tx = threadIdx.x & 31, ty = threadIdx.x >> 5;
  const float* src = sup + ((size_t)(b*S_ + s)*C_ + c0)*LK + p0;
  #pragma unroll
  for (int i=0;i<4;i++){
    int cc = ty + i*8;
    int p = p0 + tx;
    int c = c0 + cc;
    float v = 0.f;
    if (p < LK){
      v = src[(size_t)cc*LK + tx];
      float dv = expf(-(float)(c & ~1) * (9.210340371976184f / 1024.f));
      float arg = (float)p * dv;
      v += (c & 1) ? cosf(arg) : sinf(arg);
    }
    t[cc][tx] = v;
  }
  __syncthreads();
  u16* dkc = kc + ((size_t)((s*B_ + b)*LKP + p0))*C_ + c0;
  #pragma unroll
  for (int i=0;i<4;i++){ int pp = ty + i*8; dkc[(size_t)pp*C_ + tx] = f2b(t[tx][pp]); }
}

// ---------------- shared helpers ----------------
DEVI void stage_half(const u16* P, int64_t ld, u16* dst, int wid, int r8, int s8){
  #pragma unroll
  for (int it=0; it<2; ++it){
    int ck = wid + it*8;                              // 16 chunks of 8 rows
    gload16(P + (size_t)(ck*8 + r8)*ld + s8*8, dst + ck*512);
  }
}
DEVI bf16x8 ldsread(const u16* base, int row, int kk, int lane){
  int sl = ((kk<<2) + (lane>>4)) ^ (row & 7);
  return *(const bf16x8*)&base[row*64 + sl*8];
}

// ================= 256x256 bf16 MFMA GEMM (dbuf; A staged early, B mid-compute) =================
// (unchanged round-10 engine; used for k-proj, q-proj, Vt)
template<int CEPI, bool FIRST, bool FINAL, bool BIAS>
__global__ __launch_bounds__(512,1) void k8(
    const u16* __restrict__ A, const u16* __restrict__ Bm, void* __restrict__ Cm,
    const float* __restrict__ bias, const float* __restrict__ basep, const float* __restrict__ Mb,
    int tilesM, int64_t lda, int64_t ldb, int64_t ldc, int NT,
    int bdiv, int64_t aS0, int64_t aS1, int64_t bS0, int64_t bS1,
    int64_t cS0, int64_t cS1, int64_t aZ, int64_t bZ, int64_t cZ,
    int biasS0, float scale, int Nmax, int Mmax, int swz){
  __shared__ __align__(16) u16 lds[2][2][16384];
  int tid = threadIdx.x, lane = tid & 63, wid = tid >> 6;
  int bx = blockIdx.x;
  int mt, ntile;
  if (swz == 2){ int x = bx & 7, j = bx >> 3; mt = 2*x + (j >> 2); ntile = j & 3; }
  else {
    if (swz == 1) bx = (bx & 7) * (gridDim.x >> 3) + (bx >> 3);
    mt = bx % tilesM; ntile = bx / tilesM;
  }
  int z = blockIdx.y, i0 = z / bdiv, i1 = z % bdiv;
  int iz = blockIdx.z;
  const u16* Ab = A + i0*aS0 + i1*aS1 + iz*aZ + (size_t)mt*256*lda;
  const u16* Bb = Bm + i0*bS0 + i1*bS1 + iz*bZ + (size_t)ntile*256*ldb;
  int r8 = lane >> 3, s8 = (lane & 7) ^ r8;
  int wr = wid >> 2, wc = wid & 3;

  f32x4 acc[8][4];
  #pragma unroll
  for (int i=0;i<8;i++)
    #pragma unroll
    for (int j=0;j<4;j++) acc[i][j] = (f32x4){0.f,0.f,0.f,0.f};

  const u16 *ApS = Ab, *BpS = Bb;
  stage_half(ApS,                   lda, &lds[0][0][0],    wid, r8, s8);
  stage_half(ApS + (size_t)128*lda, lda, &lds[0][0][8192], wid, r8, s8);
  stage_half(BpS,                   ldb, &lds[0][1][0],    wid, r8, s8);
  stage_half(BpS + (size_t)128*ldb, ldb, &lds[0][1][8192], wid, r8, s8);
  ApS += 64; BpS += 64;

  for (int t = 0; t < NT; ++t){
    int cur = t & 1, nxt = cur ^ 1;
    bool pf = (t + 1 < NT);
    const u16* lA = &lds[cur][0][0];
    const u16* lB = &lds[cur][1][0];
    u16* sA = &lds[nxt][0][0];
    u16* sB = &lds[nxt][1][0];
    if (pf){
      stage_half(ApS,                   lda, sA,        wid, r8, s8);
      stage_half(ApS + (size_t)128*lda, lda, sA + 8192, wid, r8, s8);
      asm volatile("s_waitcnt vmcnt(4)" ::: "memory");
    } else {
      asm volatile("s_waitcnt vmcnt(0)" ::: "memory");
    }
    asm volatile("s_barrier" ::: "memory");

    bf16x8 bfr[4][2];
    #pragma unroll
    for (int jn=0;jn<4;jn++)
      #pragma unroll
      for (int kk=0;kk<2;kk++)
        bfr[jn][kk] = ldsread(lB, wc*64 + jn*16 + (lane & 15), kk, lane);

    #pragma unroll
    for (int p = 0; p < 4; ++p){
      bf16x8 af[2][2];
      #pragma unroll
      for (int dm=0;dm<2;dm++)
        #pragma unroll
        for (int kk=0;kk<2;kk++)
          af[dm][kk] = ldsread(lA, wr*128 + (p*2+dm)*16 + (lane & 15), kk, lane);
      __builtin_amdgcn_s_setprio(1);
      #pragma unroll
      for (int dm=0;dm<2;dm++)
        #pragma unroll
        for (int jn=0;jn<4;jn++)
          #pragma unroll
          for (int kk=0;kk<2;kk++)
            acc[p*2+dm][jn] = __builtin_amdgcn_mfma_f32_16x16x32_bf16(af[dm][kk], bfr[jn][kk], acc[p*2+dm][jn], 0,0,0);
      __builtin_amdgcn_s_setprio(0);
      if (p == 0 && pf) stage_half(BpS,                   ldb, sB,        wid, r8, s8);
      if (p == 1 && pf) stage_half(BpS + (size_t)128*ldb, ldb, sB + 8192, wid, r8, s8);
    }
    asm volatile("s_barrier" ::: "memory");
    if (pf){ ApS += 64; BpS += 64; }
  }

  int g = lane >> 4, c16 = lane & 15;
  if constexpr (CEPI == 0){
    u16* Cb = (u16*)Cm + i0*cS0 + i1*cS1 + iz*cZ;
    #pragma unroll
    for (int jn=0;jn<4;jn++){
      int n = ntile*256 + wc*64 + jn*16 + c16;
      if (n >= Nmax) continue;
      float bv = 0.f;
      if (BIAS) bv = bias[(size_t)i0*biasS0 + n];
      #pragma unroll
      for (int im=0;im<8;im++){
        int m = mt*256 + wr*128 + im*16 + g*4;
        if (m >= Mmax) continue;
        #pragma unroll
        for (int r=0;r<4;r++)
          Cb[(size_t)(m + r)*ldc + n] = f2b((acc[im][jn][r] + bv)*scale);
      }
    }
  } else {
    float* Cb = (float*)Cm + i0*cS0 + i1*cS1 + iz*cZ;
    const float* Bs = basep + i0*cS0 + i1*cS1 + iz*cZ;
    #pragma unroll
    for (int jn=0;jn<4;jn++){
      int n = ntile*256 + wc*64 + jn*16 + c16;
      float mbv = 0.f;
      if (FINAL) mbv = Mb[n];
      #pragma unroll
      for (int im=0;im<8;im++){
        int m = mt*256 + wr*128 + im*16 + g*4;
        float* p = Cb + (size_t)n*ldc + m;
        float4 v;
        v.x = acc[im][jn][0]; v.y = acc[im][jn][1]; v.z = acc[im][jn][2]; v.w = acc[im][jn][3];
        if (!FIRST){
          float4 old = *(const float4*)p;
          v.x += old.x; v.y += old.y; v.z += old.z; v.w += old.w;
        }
        if (FINAL){
          float4 bs = *(const float4*)(Bs + (size_t)n*ldc + m);
          v.x = bs.x * fmaxf(0.2f*v.x + mbv, 0.f);
          v.y = bs.y * fmaxf(0.2f*v.y + mbv, 0.f);
          v.z = bs.z * fmaxf(0.2f*v.z + mbv, 0.f);
          v.w = bs.w * fmaxf(0.2f*v.w + mbv, 0.f);
        }
        *(float4*)p = v;
      }
    }
  }
}

// ================= k8p: 8-phase PV GEMM (m201 schedule, plain HIP) =================
// out[b][c][l] (+)= Vt[b][c][:] . attn[b][l][:]  -- A = Vt (M=1024,c), B = attn (N=4096,l).
// 256x256 tile, 8 waves 2Mx4N, BK=64, 2 K-tiles per iteration, 8 phases.
// Phase = {ds_read A-quadrant (+B at ph1/ph5); stage 1 half-tile; [vmcnt]; barrier;
//          setprio(1); 16 MFMA; setprio(0); barrier}.
// Staging map (iter i, u=2i): ph1:A(u+1)lo+hi; ph2-3:B(u+2); ph5-6:A(u+2); ph7-8:B(u+3).
// Region-death audit: B regions die after ph1/ph5 (read once into bfr); A after ph4/ph8.
// vmcnt(4) at ph4/ph8: youngest-4 outstanding = just-issued stream; all data read by the
// following phases is provably older -> complete. Guards degrade to vmcnt(0) at tails.
#define K8P_PHASE(LA, LB, P, READB, STAGE, VM)                                         \
  {                                                                                    \
    if (READB){                                                                        \
      _Pragma("unroll")                                                                \
      for (int jn=0;jn<4;jn++)                                                         \
        _Pragma("unroll")                                                              \
        for (int kk=0;kk<2;kk++)                                                       \
          bfr[jn][kk] = ldsread((LB), wc*64 + jn*16 + c16, kk, lane);                  \
    }                                                                                  \
    bf16x8 af[2][2];                                                                   \
    _Pragma("unroll")                                                                  \
    for (int dm=0;dm<2;dm++)                                                           \
      _Pragma("unroll")                                                                \
      for (int kk=0;kk<2;kk++)                                                         \
        af[dm][kk] = ldsread((LA), wr*128 + ((P)*2+dm)*16 + c16, kk, lane);            \
    STAGE;                                                                             \
    VM;                                                                                \
    asm volatile("s_barrier" ::: "memory");                                            \
    __builtin_amdgcn_s_setprio(1);                                                     \
    _Pragma("unroll")                                                                  \
    for (int dm=0;dm<2;dm++)                                                           \
      _Pragma("unroll")                                                                \
      for (int jn=0;jn<4;jn++)                                                         \
        _Pragma("unroll")                                                              \
        for (int kk=0;kk<2;kk++)                                                       \
          acc[(P)*2+dm][jn] = __builtin_amdgcn_mfma_f32_16x16x32_bf16(af[dm][kk], bfr[jn][kk], acc[(P)*2+dm][jn], 0,0,0); \
    __builtin_amdgcn_s_setprio(0);                                                     \
    asm volatile("s_barrier" ::: "memory");                                            \
  }

template<bool FIRST, bool FINAL>
__global__ __launch_bounds__(512,1) void k8p(
    const u16* __restrict__ A, const u16* __restrict__ Bm, float* __restrict__ Cm,
    const float* __restrict__ basep, const float* __restrict__ Mb,
    int KVP, int NT){
  __shared__ __align__(16) u16 lds[2][2][16384];   // [parity][A|B][256*64]
  int tid = threadIdx.x, lane = tid & 63, wid = tid >> 6;
  int bx = blockIdx.x;
  int x = bx & 7, j = bx >> 3;
  int ntile = x*2 + (j >> 2);                      // 16 l-tiles, 2 per XCD
  int mt = j & 3;                                  // 4 c-tiles
  int b = blockIdx.y;
  const u16* Ab = A + ((size_t)b*C_ + (size_t)mt*256)*KVP;    // Vt
  const u16* Bb = Bm + ((size_t)b*LQ + (size_t)ntile*256)*KVP; // attn
  int64_t lda = KVP, ldb = KVP;
  int r8 = lane >> 3, s8 = (lane & 7) ^ r8;
  int c16 = lane & 15, g = lane >> 4;
  int wr = wid >> 2, wc = wid & 3;

  f32x4 acc[8][4];
  #pragma unroll
  for (int i=0;i<8;i++)
    #pragma unroll
    for (int jn=0;jn<4;jn++) acc[i][jn] = (f32x4){0.f,0.f,0.f,0.f};
  bf16x8 bfr[4][2];

  // prologue: B0, A0, B1 (12 loads); vmcnt(4) allows B1 outstanding, tile0 complete.
  stage_half(Bb,                   ldb, &lds[0][1][0],    wid, r8, s8);
  stage_half(Bb + (size_t)128*ldb, ldb, &lds[0][1][8192], wid, r8, s8);
  stage_half(Ab,                   lda, &lds[0][0][0],    wid, r8, s8);
  stage_half(Ab + (size_t)128*lda, lda, &lds[0][0][8192], wid, r8, s8);
  stage_half(Bb + 64,                   ldb, &lds[1][1][0],    wid, r8, s8);
  stage_half(Bb + (size_t)128*ldb + 64, ldb, &lds[1][1][8192], wid, r8, s8);
  asm volatile("s_waitcnt vmcnt(4)" ::: "memory");
  asm volatile("s_barrier" ::: "memory");

  const u16* lA0 = &lds[0][0][0]; const u16* lB0 = &lds[0][1][0];
  const u16* lA1 = &lds[1][0][0]; const u16* lB1 = &lds[1][1][0];

  int nPairs = NT >> 1;
  for (int i = 0; i < nPairs; ++i){
    int u = 2*i;
    bool s2 = (u + 2 < NT), s3 = (u + 3 < NT);
    // ---- tile u (buf0), phases 1..4 ----
    K8P_PHASE(lA0, lB0, 0, true,
      { stage_half(Ab + (size_t)(u+1)*64,                     lda, &lds[1][0][0],    wid, r8, s8);
        stage_half(Ab + (size_t)128*lda + (size_t)(u+1)*64,   lda, &lds[1][0][8192], wid, r8, s8); },
      {});
    K8P_PHASE(lA0, lB0, 1, false,
      { if (s2) stage_half(Bb + (size_t)(u+2)*64,             ldb, &lds[0][1][0],    wid, r8, s8); },
      {});
    K8P_PHASE(lA0, lB0, 2, false,
      { if (s2) stage_half(Bb + (size_t)128*ldb + (size_t)(u+2)*64, ldb, &lds[0][1][8192], wid, r8, s8); },
      {});
    K8P_PHASE(lA0, lB0, 3, false, {},
      { if (s2) { asm volatile("s_waitcnt vmcnt(4)" ::: "memory"); }
        else    { asm volatile("s_waitcnt vmcnt(0)" ::: "memory"); } });
    // ---- tile u+1 (buf1), phases 5..8 ----
    K8P_PHASE(lA1, lB1, 0, true,
      { if (s2) stage_half(Ab + (size_t)(u+2)*64,             lda, &lds[0][0][0],    wid, r8, s8); },
      {});
    K8P_PHASE(lA1, lB1, 1, false,
      { if (s2) stage_half(Ab + (size_t)128*lda + (size_t)(u+2)*64, lda, &lds[0][0][8192], wid, r8, s8); },
      {});
    K8P_PHASE(lA1, lB1, 2, false,
      { if (s3) stage_half(Bb + (size_t)(u+3)*64,             ldb, &lds[1][1][0],    wid, r8, s8); },
      {});
    K8P_PHASE(lA1, lB1, 3, false,
      { if (s3) stage_half(Bb + (size_t)128*ldb + (size_t)(u+3)*64, ldb, &lds[1][1][8192], wid, r8, s8); },
      { if (s3) { asm volatile("s_waitcnt vmcnt(4)" ::: "memory"); }
        else    { asm volatile("s_waitcnt vmcnt(0)" ::: "memory"); } });
  }
  if (NT & 1){
    // tail tile NT-1 (even parity -> buf0); all data landed at last vmcnt(0).
    K8P_PHASE(lA0, lB0, 0, true,  {}, {});
    K8P_PHASE(lA0, lB0, 1, false, {}, {});
    K8P_PHASE(lA0, lB0, 2, false, {}, {});
    K8P_PHASE(lA0, lB0, 3, false, {}, {});
  }

  // epilogue: m = c-index, n = l-index; out[b][m][n]
  float* Cb = Cm + (size_t)b*C_*LQ;
  const float* Bs = basep + (size_t)b*C_*LQ;
  #pragma unroll
  for (int jn=0;jn<4;jn++){
    int n = ntile*256 + wc*64 + jn*16 + c16;
    #pragma unroll
    for (int im=0;im<8;im++){
      int m0 = mt*256 + wr*128 + im*16 + g*4;
      #pragma unroll
      for (int r=0;r<4;r++){
        int m = m0 + r;
        float v = acc[im][jn][r];
        float* p = Cb + (size_t)m*LQ + n;
        if (!FIRST) v += *p;
        if (FINAL){
          float bs = Bs[(size_t)m*LQ + n];
          v = bs * fmaxf(0.2f*v + Mb[m], 0.f);
        }
        *p = v;
      }
    }
  }
}

// ================= fused QK^T + softmax -> attn[b][l][zz*400..] (dense kv layout) =================
// Round-10 version (known-good): 128 q-rows/block, 8 waves x 16 rows, acc[25],
// ALL indices compile-time (rule #20). Dense-kv output addressing.
__global__ __launch_bounds__(512) void k_scores(
    const u16* __restrict__ qws, const u16* __restrict__ kws,
    u16* __restrict__ attn, int h0, int KVP, int padw, int nz){
  __shared__ __align__(16) u16 lQ[128*64];
  __shared__ __align__(16) u16 lK[400*64];
  int tid = threadIdx.x, lane = tid & 63, wid = tid >> 6;
  int m0 = blockIdx.x * 128;
  int b = blockIdx.y;
  int zz = blockIdx.z;
  int s = zz % 5, h = h0 + zz / 5;
  const u16* Qp = qws + ((size_t)(h*B_ + b)*LQ + m0)*D_;
  const u16* Kp = kws + ((size_t)((h*S_ + s)*B_ + b))*((size_t)LKP*D_);
  int r8 = lane >> 3, s8 = (lane & 7) ^ r8;
  f32x4 acc[25];
  #pragma unroll
  for (int t=0;t<25;t++) acc[t] = (f32x4){0.f,0.f,0.f,0.f};
  int wm = wid * 16;
  for (int k0 = 0; k0 < 256; k0 += 64){
    __syncthreads();
    #pragma unroll
    for (int c = 0; c < 2; ++c){
      int cc = wid + c*8;
      int row = cc*8 + r8;
      gload16(Qp + (size_t)row*D_ + k0 + s8*8, &lQ[cc*512]);
    }
    for (int cc = wid; cc < 50; cc += 8){
      int row = cc*8 + r8;
      gload16(Kp + (size_t)row*D_ + k0 + s8*8, &lK[cc*512]);
    }
    __syncthreads();
    #pragma unroll
    for (int kk = 0; kk < 2; ++kk){
      int rowA = wm + (lane & 15);
      int slA = ((kk<<2) + (lane>>4)) ^ (rowA & 7);
      bf16x8 af = *(const bf16x8*)&lQ[rowA*64 + slA*8];
      #pragma unroll
      for (int t=0;t<25;t++){
        int rowB = t*16 + (lane & 15);
        int slB = ((kk<<2) + (lane>>4)) ^ (rowB & 7);
        bf16x8 bf = *(const bf16x8*)&lK[rowB*64 + slB*8];
        acc[t] = __builtin_amdgcn_mfma_f32_16x16x32_bf16(af, bf, acc[t], 0,0,0);
      }
    }
  }
  float mx[4] = {-1e30f,-1e30f,-1e30f,-1e30f};
  #pragma unroll
  for (int t=0;t<25;t++)
    #pragma unroll
    for (int r=0;r<4;r++) mx[r] = fmaxf(mx[r], acc[t][r]);
  #pragma unroll
  for (int r=0;r<4;r++){
    mx[r] = fmaxf(mx[r], __shfl_xor(mx[r], 1));
    mx[r] = fmaxf(mx[r], __shfl_xor(mx[r], 2));
    mx[r] = fmaxf(mx[r], __shfl_xor(mx[r], 4));
    mx[r] = fmaxf(mx[r], __shfl_xor(mx[r], 8));
  }
  float sm[4] = {0.f,0.f,0.f,0.f};
  #pragma unroll
  for (int t=0;t<25;t++)
    #pragma unroll
    for (int r=0;r<4;r++){ float e = __expf(acc[t][r] - mx[r]); acc[t][r] = e; sm[r] += e; }
  #pragma unroll
  for (int r=0;r<4;r++){
    sm[r] += __shfl_xor(sm[r], 1);
    sm[r] += __shfl_xor(sm[r], 2);
    sm[r] += __shfl_xor(sm[r], 4);
    sm[r] += __shfl_xor(sm[r], 8);
    sm[r] = 1.f / sm[r];
  }
  u16* ap = attn + ((size_t)b*LQ + m0 + wm)*KVP + (size_t)zz*400;
  int g = lane >> 4, c16 = lane & 15;
  #pragma unroll
  for (int t=0;t<25;t++)
    #pragma unroll
    for (int r=0;r<4;r++)
      ap[(size_t)(g*4 + r)*KVP + t*16 + c16] = f2b(acc[t][r] * sm[r]);
  if (zz == nz - 1 && padw > 0){
    u16* base2 = attn + ((size_t)b*LQ + m0)*KVP + (KVP - padw);
    int total = 128 * padw;
    for (int i = tid; i < total; i += 512){
      int rr = i / padw, cc = i % padw;
      base2[(size_t)rr*KVP + cc] = 0;
    }
  }
}

extern "C" void kernel_launch(void* const* d_in, const int* in_sizes, int n_in,
                              void* d_out, int out_size, void* d_ws, size_t ws_size,
                              hipStream_t stream){
  const float* base = (const float*)d_in[0];
  const float* sup  = (const float*)d_in[1];
  const float* Qw   = (const float*)d_in[2];
  const float* Qb   = (const float*)d_in[3];
  const float* Kw   = (const float*)d_in[4];
  const float* Kb   = (const float*)d_in[5];
  const float* Mw   = (const float*)d_in[6];
  const float* Mb   = (const float*)d_in[7];
  float* out = (float*)d_out;
  char* ws = (char*)d_ws;

  const int GH = (ws_size >= 247988224ull) ? 2 : 1;   // heads per group
  const int NG = H_ / GH;
  const int NZ = GH * 5;
  const int KVP = (NZ*400 + 63) & ~63;                // 4032 (GH=2) / 2048 (GH=1)
  const int NT = KVP / 64;
  const int PADW = KVP - NZ*400;

  u16* wQw = (u16*)(ws + 0);            //  2,097,152  [H][D][C]
  u16* wKw = (u16*)(ws + 2097152);      //  2,097,152  [H][D][C]
  u16* wMw = (u16*)(ws + 4194304);      //  8,388,608  [C][H*C]
  u16* wKC = (u16*)(ws + 12582912);     // 18,350,080  smat [S*B][448][C]
  u16* wK  = (u16*)(ws + 30932992);     // 18,350,080  k [H][S][B][448][D]
  u16* wQ  = (u16*)(ws + 49283072);     // 33,554,432  q [H][B][LQ][D]
  u16* wVt = (u16*)(ws + 82837504);     // B*C*KVP*2   Vt [B][C][KVP]
  u16* wAT = (u16*)(ws + 82837504 + (size_t)B_*C_*KVP*2);  // B*LQ*KVP*2  attn [B][LQ][KVP]
  u16* wXb = wAT;                       // Xb [B][LQ][C] aliases attn (dead after q-proj)

  const int BIG = 1 << 30;

  k_cvt<<<1024, 256, 0, stream>>>(Qw, wQw, 262144);
  k_cvt<<<1024, 256, 0, stream>>>(Kw, wKw, 262144);
  k_cvt<<<4096, 256, 0, stream>>>(Mw, wMw, 1048576);
  k_transpose_x<<<dim3(128, 32, 4), 256, 0, stream>>>(base, wXb);
  k_build_smat<<<dim3(14, 32, 20), 256, 0, stream>>>(sup, wKC);

  // k-proj: k[h][s][b] = smat[s][b] @ Kw[h]^T + Kb   (M=448, N=256, K=1024)
  k8<0,false,false,true><<<dim3(2, 80, 1), 512, 0, stream>>>(
      wKC, wKw, wK, Kb, nullptr, nullptr,
      2, C_, C_, D_, 16,
      20, 0, (int64_t)LKP*C_, (int64_t)D_*C_, 0,
      (int64_t)S_*B_*LKP*D_, (int64_t)LKP*D_, 0, 0, 0,
      D_, 1.f, BIG, LKP, 0);

  // q-proj: q[h][b] = (Xb[b] @ Qw[h]^T + Qb)/16      (M=4096, N=256, K=1024)
  k8<0,false,false,true><<<dim3(16, 16, 1), 512, 0, stream>>>(
      wXb, wQw, wQ, Qb, nullptr, nullptr,
      16, C_, C_, D_, 16,
      4, 0, (int64_t)LQ*C_, (int64_t)D_*C_, 0,
      (int64_t)B_*LQ*D_, (int64_t)LQ*D_, 0, 0, 0,
      D_, 1.f/16.f, BIG, BIG, 1);

  for (int g = 0; g < NG; ++g){
    // Vt[b][c][zz*400+j] = sum_c' Mw[c][(g*GH+zz/5)*C+c'] * smat[zz%5][b][j][c']
    k8<0,false,false,false><<<dim3(8, NZ, 4), 512, 0, stream>>>(
        wMw + (size_t)(g*GH)*C_, wKC, wVt, nullptr, nullptr, nullptr,
        4, (int64_t)H_*C_, C_, KVP, 16,
        5, (int64_t)C_, 0, 0, (int64_t)B_*LKP*C_,
        2000, 400, 0, (int64_t)LKP*C_, (int64_t)C_*KVP,
        0, 1.f, 400, BIG, 0);

    // scores+softmax (dense kv layout)
    k_scores<<<dim3(32, 4, NZ), 512, 0, stream>>>(wQ, wK, wAT, g*GH, KVP, PADW, NZ);

    // PV (8-phase k8p): out[b][c][l] (+)= Vt[b][c][:] . attn[b][l][:]
    if (g == 0 && NG > 1){
      k8p<true,false><<<dim3(64, 4), 512, 0, stream>>>(wVt, wAT, out, base, Mb, KVP, NT);
    } else if (g == NG - 1){
      k8p<false,true><<<dim3(64, 4), 512, 0, stream>>>(wVt, wAT, out, base, Mb, KVP, NT);
    } else {
      k8p<false,false><<<dim3(64, 4), 512, 0, stream>>>(wVt, wAT, out, base, Mb, KVP, NT);
    }
  }
}

// Round 13
// 707.333 us; speedup vs baseline: 1.1074x; 1.1074x over previous
//
#include <hip/hip_runtime.h>
#include <stdint.h>

#define DEVI __device__ __forceinline__

typedef __attribute__((ext_vector_type(8))) short bf16x8;
typedef __attribute__((ext_vector_type(4))) float f32x4;
typedef __attribute__((ext_vector_type(4))) unsigned short us4;
typedef unsigned short u16;

constexpr int B_ = 4, S_ = 5, H_ = 4, C_ = 1024, D_ = 256;
constexpr int LQ = 4096, LK = 400, LKP = 448;

DEVI u16 f2b(float f){
  uint32_t x = __float_as_uint(f);
  uint32_t r = (x + 0x7FFFu + ((x >> 16) & 1u)) >> 16;
  return (u16)r;
}

typedef __attribute__((address_space(1))) const void ASG;
typedef __attribute__((address_space(3))) void ASL;
DEVI void gload16(const void* g, void* l){
  __builtin_amdgcn_global_load_lds((ASG*)g, (ASL*)l, 16, 0, 0);
}

// ---------------- fp32 -> bf16 convert (3 arrays, one launch) ----------------
__global__ __launch_bounds__(256) void k_cvt3(
    const float* __restrict__ s0, u16* __restrict__ d0, int n0,
    const float* __restrict__ s1, u16* __restrict__ d1, int n1,
    const float* __restrict__ s2, u16* __restrict__ d2, int n2){
  int i = blockIdx.x*256 + threadIdx.x;
  const float* s; u16* d; int idx;
  if (i < n0){ s = s0; d = d0; idx = i; }
  else if (i < n0 + n1){ s = s1; d = d1; idx = i - n0; }
  else if (i < n0 + n1 + n2){ s = s2; d = d2; idx = i - n0 - n1; }
  else return;
  float4 v = ((const float4*)s)[idx];
  us4 o; o.x = f2b(v.x); o.y = f2b(v.y); o.z = f2b(v.z); o.w = f2b(v.w);
  *(us4*)(d + (size_t)idx*4) = o;
}

// ---------------- base_feat [B][C][LQ] -> Xb bf16 [B][LQ][C] ----------------
__global__ __launch_bounds__(256) void k_transpose_x(const float* __restrict__ base, u16* __restrict__ Xb){
  __shared__ float t[32][33];
  int l0 = blockIdx.x*32, c0 = blockIdx.y*32, b = blockIdx.z;
  int tx = threadIdx.x & 31, ty = threadIdx.x >> 5;
  const float* src = base + ((size_t)b*C_ + c0)*LQ + l0;
  #pragma unroll
  for (int i=0;i<4;i++){ int cc = ty + i*8; t[cc][tx] = src[(size_t)cc*LQ + tx]; }
  __syncthreads();
  u16* dst = Xb + ((size_t)b*LQ + l0)*C_ + c0;
  #pragma unroll
  for (int i=0;i<4;i++){ int ll = ty + i*8; dst[(size_t)ll*C_ + tx] = f2b(t[tx][ll]); }
}

// ---------------- support + pe -> smat [S][B][448][C] (rows 400..447 zero) ----------------
__global__ __launch_bounds__(256) void k_build_smat(const float* __restrict__ sup, u16* __restrict__ kc){
  __shared__ float t[32][33];
  int p0 = blockIdx.x*32, c0 = blockIdx.y*32;
  int s = blockIdx.z / B_, b = blockIdx.z % B_;
  int tx = threadIdx.x & 31, ty = threadIdx.x >> 5;
  const float* src = sup + ((size_t)(b*S_ + s)*C_ + c0)*LK + p0;
  #pragma unroll
  for (int i=0;i<4;i++){
    int cc = ty + i*8;
    int p = p0 + tx;
    int c = c0 + cc;
    float v = 0.f;
    if (p < LK){
      v = src[(size_t)cc*LK + tx];
      float dv = expf(-(float)(c & ~1) * (9.210340371976184f / 1024.f));
      float arg = (float)p * dv;
      v += (c & 1) ? cosf(arg) : sinf(arg);
    }
    t[cc][tx] = v;
  }
  __syncthreads();
  u16* dkc = kc + ((size_t)((s*B_ + b)*LKP + p0))*C_ + c0;
  #pragma unroll
  for (int i=0;i<4;i++){ int pp = ty + i*8; dkc[(size_t)pp*C_ + tx] = f2b(t[tx][pp]); }
}

// ---------------- shared helpers ----------------
DEVI void stage_half(const u16* P, int64_t ld, u16* dst, int wid, int r8, int s8){
  #pragma unroll
  for (int it=0; it<2; ++it){
    int ck = wid + it*8;                              // 16 chunks of 8 rows
    gload16(P + (size_t)(ck*8 + r8)*ld + s8*8, dst + ck*512);
  }
}
DEVI bf16x8 ldsread(const u16* base, int row, int kk, int lane){
  int sl = ((kk<<2) + (lane>>4)) ^ (row & 7);
  return *(const bf16x8*)&base[row*64 + sl*8];
}

// ================= 256x256 bf16 MFMA GEMM (dbuf; A staged early, B mid-compute) =================
// C[M][N] = A[M][K] * B[N][K]^T ; 512 threads, 8 waves 2Mx4N; BK=64.
// Issue schedule per iter t: stage A(t+1) [4 gloads]; vmcnt(4) (in-order retire =>
// tile t's A+B complete, only A(t+1) outstanding); barrier; compute 4 quadrants
// with B(t+1)-lo/-hi staged after quadrants 0/1; barrier. Last iter: vmcnt(0).
// CEPI 0: bf16 row-major store (+bias)*scale, n<Nmax, m<Mmax.
// CEPI 1: fp32 transposed store C[n*ldc+m] (+=old unless FIRST);
//         FINAL: out = base*relu(0.2*(old+acc)+Mb[n]).
// swz: 0 none; 1 generic XCD-contig (gx%8==0); 2 PV mapping (grid.x==64, tilesM=16).
template<int CEPI, bool FIRST, bool FINAL, bool BIAS>
__global__ __launch_bounds__(512,1) void k8(
    const u16* __restrict__ A, const u16* __restrict__ Bm, void* __restrict__ Cm,
    const float* __restrict__ bias, const float* __restrict__ basep, const float* __restrict__ Mb,
    int tilesM, int64_t lda, int64_t ldb, int64_t ldc, int NT,
    int bdiv, int64_t aS0, int64_t aS1, int64_t bS0, int64_t bS1,
    int64_t cS0, int64_t cS1, int64_t aZ, int64_t bZ, int64_t cZ,
    int biasS0, float scale, int Nmax, int Mmax, int swz){
  __shared__ __align__(16) u16 lds[2][2][16384];
  int tid = threadIdx.x, lane = tid & 63, wid = tid >> 6;
  int bx = blockIdx.x;
  int mt, ntile;
  if (swz == 2){ int x = bx & 7, j = bx >> 3; mt = 2*x + (j >> 2); ntile = j & 3; }
  else {
    if (swz == 1) bx = (bx & 7) * (gridDim.x >> 3) + (bx >> 3);
    mt = bx % tilesM; ntile = bx / tilesM;
  }
  int z = blockIdx.y, i0 = z / bdiv, i1 = z % bdiv;
  int iz = blockIdx.z;
  const u16* Ab = A + i0*aS0 + i1*aS1 + iz*aZ + (size_t)mt*256*lda;
  const u16* Bb = Bm + i0*bS0 + i1*bS1 + iz*bZ + (size_t)ntile*256*ldb;
  int r8 = lane >> 3, s8 = (lane & 7) ^ r8;
  int wr = wid >> 2, wc = wid & 3;

  f32x4 acc[8][4];
  #pragma unroll
  for (int i=0;i<8;i++)
    #pragma unroll
    for (int j=0;j<4;j++) acc[i][j] = (f32x4){0.f,0.f,0.f,0.f};

  // prologue: stage tile 0 (A then B) into buf 0
  const u16 *ApS = Ab, *BpS = Bb;
  stage_half(ApS,                   lda, &lds[0][0][0],    wid, r8, s8);
  stage_half(ApS + (size_t)128*lda, lda, &lds[0][0][8192], wid, r8, s8);
  stage_half(BpS,                   ldb, &lds[0][1][0],    wid, r8, s8);
  stage_half(BpS + (size_t)128*ldb, ldb, &lds[0][1][8192], wid, r8, s8);
  ApS += 64; BpS += 64;

  for (int t = 0; t < NT; ++t){
    int cur = t & 1, nxt = cur ^ 1;
    bool pf = (t + 1 < NT);
    const u16* lA = &lds[cur][0][0];
    const u16* lB = &lds[cur][1][0];
    u16* sA = &lds[nxt][0][0];
    u16* sB = &lds[nxt][1][0];
    if (pf){
      // stage A(t+1) early: A stream has >= 1 full iteration of latency slack
      stage_half(ApS,                   lda, sA,        wid, r8, s8);
      stage_half(ApS + (size_t)128*lda, lda, sA + 8192, wid, r8, s8);
      asm volatile("s_waitcnt vmcnt(4)" ::: "memory");   // tile t (A+B) complete; A(t+1) in flight
    } else {
      asm volatile("s_waitcnt vmcnt(0)" ::: "memory");
    }
    asm volatile("s_barrier" ::: "memory");

    bf16x8 bfr[4][2];
    #pragma unroll
    for (int jn=0;jn<4;jn++)
      #pragma unroll
      for (int kk=0;kk<2;kk++)
        bfr[jn][kk] = ldsread(lB, wc*64 + jn*16 + (lane & 15), kk, lane);

    #pragma unroll
    for (int p = 0; p < 4; ++p){
      bf16x8 af[2][2];
      #pragma unroll
      for (int dm=0;dm<2;dm++)
        #pragma unroll
        for (int kk=0;kk<2;kk++)
          af[dm][kk] = ldsread(lA, wr*128 + (p*2+dm)*16 + (lane & 15), kk, lane);
      __builtin_amdgcn_s_setprio(1);
      #pragma unroll
      for (int dm=0;dm<2;dm++)
        #pragma unroll
        for (int jn=0;jn<4;jn++)
          #pragma unroll
          for (int kk=0;kk<2;kk++)
            acc[p*2+dm][jn] = __builtin_amdgcn_mfma_f32_16x16x32_bf16(af[dm][kk], bfr[jn][kk], acc[p*2+dm][jn], 0,0,0);
      __builtin_amdgcn_s_setprio(0);
      // stage B(t+1) halves mid-compute (B stream is L2-resident; ~half-iter slack)
      if (p == 0 && pf) stage_half(BpS,                   ldb, sB,        wid, r8, s8);
      if (p == 1 && pf) stage_half(BpS + (size_t)128*ldb, ldb, sB + 8192, wid, r8, s8);
    }
    asm volatile("s_barrier" ::: "memory");
    if (pf){ ApS += 64; BpS += 64; }
  }

  int g = lane >> 4, c16 = lane & 15;
  if constexpr (CEPI == 0){
    u16* Cb = (u16*)Cm + i0*cS0 + i1*cS1 + iz*cZ;
    #pragma unroll
    for (int jn=0;jn<4;jn++){
      int n = ntile*256 + wc*64 + jn*16 + c16;
      if (n >= Nmax) continue;
      float bv = 0.f;
      if (BIAS) bv = bias[(size_t)i0*biasS0 + n];
      #pragma unroll
      for (int im=0;im<8;im++){
        int m = mt*256 + wr*128 + im*16 + g*4;
        if (m >= Mmax) continue;
        #pragma unroll
        for (int r=0;r<4;r++)
          Cb[(size_t)(m + r)*ldc + n] = f2b((acc[im][jn][r] + bv)*scale);
      }
    }
  } else {
    float* Cb = (float*)Cm + i0*cS0 + i1*cS1 + iz*cZ;
    const float* Bs = basep + i0*cS0 + i1*cS1 + iz*cZ;
    #pragma unroll
    for (int jn=0;jn<4;jn++){
      int n = ntile*256 + wc*64 + jn*16 + c16;
      float mbv = 0.f;
      if (FINAL) mbv = Mb[n];
      #pragma unroll
      for (int im=0;im<8;im++){
        int m = mt*256 + wr*128 + im*16 + g*4;
        float* p = Cb + (size_t)n*ldc + m;
        float4 v;
        v.x = acc[im][jn][0]; v.y = acc[im][jn][1]; v.z = acc[im][jn][2]; v.w = acc[im][jn][3];
        if (!FIRST){
          float4 old = *(const float4*)p;
          v.x += old.x; v.y += old.y; v.z += old.z; v.w += old.w;
        }
        if (FINAL){
          float4 bs = *(const float4*)(Bs + (size_t)n*ldc + m);
          v.x = bs.x * fmaxf(0.2f*v.x + mbv, 0.f);
          v.y = bs.y * fmaxf(0.2f*v.y + mbv, 0.f);
          v.z = bs.z * fmaxf(0.2f*v.z + mbv, 0.f);
          v.w = bs.w * fmaxf(0.2f*v.w + mbv, 0.f);
        }
        *(float4*)p = v;
      }
    }
  }
}

// ================= fused QK^T + softmax -> attn[b][l][zz*400..] (dense kv layout) =================
// Round-10 version (known-good): 128 q-rows/block, 8 waves x 16 rows, acc[25],
// ALL indices compile-time (rule #20). Dense-kv output addressing.
__global__ __launch_bounds__(512) void k_scores(
    const u16* __restrict__ qws, const u16* __restrict__ kws,
    u16* __restrict__ attn, int h0, int KVP, int padw, int nz){
  __shared__ __align__(16) u16 lQ[128*64];
  __shared__ __align__(16) u16 lK[400*64];
  int tid = threadIdx.x, lane = tid & 63, wid = tid >> 6;
  int m0 = blockIdx.x * 128;
  int b = blockIdx.y;
  int zz = blockIdx.z;
  int s = zz % 5, h = h0 + zz / 5;
  const u16* Qp = qws + ((size_t)(h*B_ + b)*LQ + m0)*D_;
  const u16* Kp = kws + ((size_t)((h*S_ + s)*B_ + b))*((size_t)LKP*D_);
  int r8 = lane >> 3, s8 = (lane & 7) ^ r8;
  f32x4 acc[25];
  #pragma unroll
  for (int t=0;t<25;t++) acc[t] = (f32x4){0.f,0.f,0.f,0.f};
  int wm = wid * 16;
  for (int k0 = 0; k0 < 256; k0 += 64){
    __syncthreads();
    #pragma unroll
    for (int c = 0; c < 2; ++c){
      int cc = wid + c*8;
      int row = cc*8 + r8;
      gload16(Qp + (size_t)row*D_ + k0 + s8*8, &lQ[cc*512]);
    }
    for (int cc = wid; cc < 50; cc += 8){
      int row = cc*8 + r8;
      gload16(Kp + (size_t)row*D_ + k0 + s8*8, &lK[cc*512]);
    }
    __syncthreads();
    #pragma unroll
    for (int kk = 0; kk < 2; ++kk){
      int rowA = wm + (lane & 15);
      int slA = ((kk<<2) + (lane>>4)) ^ (rowA & 7);
      bf16x8 af = *(const bf16x8*)&lQ[rowA*64 + slA*8];
      #pragma unroll
      for (int t=0;t<25;t++){
        int rowB = t*16 + (lane & 15);
        int slB = ((kk<<2) + (lane>>4)) ^ (rowB & 7);
        bf16x8 bf = *(const bf16x8*)&lK[rowB*64 + slB*8];
        acc[t] = __builtin_amdgcn_mfma_f32_16x16x32_bf16(af, bf, acc[t], 0,0,0);
      }
    }
  }
  float mx[4] = {-1e30f,-1e30f,-1e30f,-1e30f};
  #pragma unroll
  for (int t=0;t<25;t++)
    #pragma unroll
    for (int r=0;r<4;r++) mx[r] = fmaxf(mx[r], acc[t][r]);
  #pragma unroll
  for (int r=0;r<4;r++){
    mx[r] = fmaxf(mx[r], __shfl_xor(mx[r], 1));
    mx[r] = fmaxf(mx[r], __shfl_xor(mx[r], 2));
    mx[r] = fmaxf(mx[r], __shfl_xor(mx[r], 4));
    mx[r] = fmaxf(mx[r], __shfl_xor(mx[r], 8));
  }
  float sm[4] = {0.f,0.f,0.f,0.f};
  #pragma unroll
  for (int t=0;t<25;t++)
    #pragma unroll
    for (int r=0;r<4;r++){ float e = __expf(acc[t][r] - mx[r]); acc[t][r] = e; sm[r] += e; }
  #pragma unroll
  for (int r=0;r<4;r++){
    sm[r] += __shfl_xor(sm[r], 1);
    sm[r] += __shfl_xor(sm[r], 2);
    sm[r] += __shfl_xor(sm[r], 4);
    sm[r] += __shfl_xor(sm[r], 8);
    sm[r] = 1.f / sm[r];
  }
  u16* ap = attn + ((size_t)b*LQ + m0 + wm)*KVP + (size_t)zz*400;
  int g = lane >> 4, c16 = lane & 15;
  #pragma unroll
  for (int t=0;t<25;t++)
    #pragma unroll
    for (int r=0;r<4;r++)
      ap[(size_t)(g*4 + r)*KVP + t*16 + c16] = f2b(acc[t][r] * sm[r]);
  if (zz == nz - 1 && padw > 0){
    u16* base2 = attn + ((size_t)b*LQ + m0)*KVP + (KVP - padw);
    int total = 128 * padw;
    for (int i = tid; i < total; i += 512){
      int rr = i / padw, cc = i % padw;
      base2[(size_t)rr*KVP + cc] = 0;
    }
  }
}

extern "C" void kernel_launch(void* const* d_in, const int* in_sizes, int n_in,
                              void* d_out, int out_size, void* d_ws, size_t ws_size,
                              hipStream_t stream){
  const float* base = (const float*)d_in[0];
  const float* sup  = (const float*)d_in[1];
  const float* Qw   = (const float*)d_in[2];
  const float* Qb   = (const float*)d_in[3];
  const float* Kw   = (const float*)d_in[4];
  const float* Kb   = (const float*)d_in[5];
  const float* Mw   = (const float*)d_in[6];
  const float* Mb   = (const float*)d_in[7];
  float* out = (float*)d_out;
  char* ws = (char*)d_ws;

  const int GH = (ws_size >= 247988224ull) ? 2 : 1;   // heads per group
  const int NG = H_ / GH;
  const int NZ = GH * 5;
  const int KVP = (NZ*400 + 63) & ~63;                // 4032 (GH=2) / 2048 (GH=1)
  const int NT = KVP / 64;
  const int PADW = KVP - NZ*400;

  u16* wQw = (u16*)(ws + 0);            //  2,097,152  [H][D][C]
  u16* wKw = (u16*)(ws + 2097152);      //  2,097,152  [H][D][C]
  u16* wMw = (u16*)(ws + 4194304);      //  8,388,608  [C][H*C]
  u16* wKC = (u16*)(ws + 12582912);     // 18,350,080  smat [S*B][448][C]
  u16* wK  = (u16*)(ws + 30932992);     // 18,350,080  k [H][S][B][448][D]
  u16* wQ  = (u16*)(ws + 49283072);     // 33,554,432  q [H][B][LQ][D]
  u16* wVt = (u16*)(ws + 82837504);     // B*C*KVP*2   Vt [B][C][KVP]
  u16* wAT = (u16*)(ws + 82837504 + (size_t)B_*C_*KVP*2);  // B*LQ*KVP*2  attn [B][LQ][KVP]
  u16* wXb = wAT;                       // Xb [B][LQ][C] aliases attn (dead after q-proj)

  const int BIG = 1 << 30;

  k_cvt3<<<6144, 256, 0, stream>>>(Qw, wQw, 262144, Kw, wKw, 262144, Mw, wMw, 1048576);
  k_transpose_x<<<dim3(128, 32, 4), 256, 0, stream>>>(base, wXb);
  k_build_smat<<<dim3(14, 32, 20), 256, 0, stream>>>(sup, wKC);

  // k-proj: k[h][s][b] = smat[s][b] @ Kw[h]^T + Kb   (M=448, N=256, K=1024)
  k8<0,false,false,true><<<dim3(2, 80, 1), 512, 0, stream>>>(
      wKC, wKw, wK, Kb, nullptr, nullptr,
      2, C_, C_, D_, 16,
      20, 0, (int64_t)LKP*C_, (int64_t)D_*C_, 0,
      (int64_t)S_*B_*LKP*D_, (int64_t)LKP*D_, 0, 0, 0,
      D_, 1.f, BIG, LKP, 0);

  // q-proj: q[h][b] = (Xb[b] @ Qw[h]^T + Qb)/16      (M=4096, N=256, K=1024)
  k8<0,false,false,true><<<dim3(16, 16, 1), 512, 0, stream>>>(
      wXb, wQw, wQ, Qb, nullptr, nullptr,
      16, C_, C_, D_, 16,
      4, 0, (int64_t)LQ*C_, (int64_t)D_*C_, 0,
      (int64_t)B_*LQ*D_, (int64_t)LQ*D_, 0, 0, 0,
      D_, 1.f/16.f, BIG, BIG, 1);

  for (int g = 0; g < NG; ++g){
    // Vt[b][c][zz*400+j] = sum_c' Mw[c][(g*GH+zz/5)*C+c'] * smat[zz%5][b][j][c']
    k8<0,false,false,false><<<dim3(8, NZ, 4), 512, 0, stream>>>(
        wMw + (size_t)(g*GH)*C_, wKC, wVt, nullptr, nullptr, nullptr,
        4, (int64_t)H_*C_, C_, KVP, 16,
        5, (int64_t)C_, 0, 0, (int64_t)B_*LKP*C_,
        2000, 400, 0, (int64_t)LKP*C_, (int64_t)C_*KVP,
        0, 1.f, 400, BIG, 0);

    // scores+softmax (dense kv layout)
    k_scores<<<dim3(32, 4, NZ), 512, 0, stream>>>(wQ, wK, wAT, g*GH, KVP, PADW, NZ);

    // PV: out[b][c][l] (+)= attn[b][l][:] . Vt[b][c][:]   (M=4096, N=1024, K=KVP)
    // grid (64, 4): swz=2 puts all 4 nt of an mt-pair on one XCD (L2 attn reuse).
    if (g == 0 && NG > 1){
      k8<1,true,false,false><<<dim3(64, 4, 1), 512, 0, stream>>>(
          wAT, wVt, out, nullptr, base, Mb,
          16, KVP, KVP, LQ, NT,
          1, (int64_t)LQ*KVP, 0, (int64_t)C_*KVP, 0,
          (int64_t)C_*LQ, 0, 0, 0, 0,
          0, 1.f, BIG, BIG, 2);
    } else if (g == NG - 1){
      k8<1,false,true,false><<<dim3(64, 4, 1), 512, 0, stream>>>(
          wAT, wVt, out, nullptr, base, Mb,
          16, KVP, KVP, LQ, NT,
          1, (int64_t)LQ*KVP, 0, (int64_t)C_*KVP, 0,
          (int64_t)C_*LQ, 0, 0, 0, 0,
          0, 1.f, BIG, BIG, 2);
    } else {
      k8<1,false,false,false><<<dim3(64, 4, 1), 512, 0, stream>>>(
          wAT, wVt, out, nullptr, base, Mb,
          16, KVP, KVP, LQ, NT,
          1, (int64_t)LQ*KVP, 0, (int64_t)C_*KVP, 0,
          (int64_t)C_*LQ, 0, 0, 0, 0,
          0, 1.f, BIG, BIG, 2);
    }
  }
}

// Round 14
// 661.241 us; speedup vs baseline: 1.1846x; 1.0697x over previous
//
#include <hip/hip_runtime.h>
#include <stdint.h>

#define DEVI __device__ __forceinline__

typedef __attribute__((ext_vector_type(8))) short bf16x8;
typedef __attribute__((ext_vector_type(4))) float f32x4;
typedef __attribute__((ext_vector_type(4))) unsigned short us4;
typedef unsigned short u16;

constexpr int B_ = 4, S_ = 5, H_ = 4, C_ = 1024, D_ = 256;
constexpr int LQ = 4096, LK = 400;

DEVI u16 f2b(float f){
  uint32_t x = __float_as_uint(f);
  uint32_t r = (x + 0x7FFFu + ((x >> 16) & 1u)) >> 16;
  return (u16)r;
}

typedef __attribute__((address_space(1))) const void ASG;
typedef __attribute__((address_space(3))) void ASL;
DEVI void gload16(const void* g, void* l){
  __builtin_amdgcn_global_load_lds((ASG*)g, (ASL*)l, 16, 0, 0);
}

// ---------------- fp32 -> bf16 convert (3 arrays, one launch) ----------------
__global__ __launch_bounds__(256) void k_cvt3(
    const float* __restrict__ s0, u16* __restrict__ d0, int n0,
    const float* __restrict__ s1, u16* __restrict__ d1, int n1,
    const float* __restrict__ s2, u16* __restrict__ d2, int n2){
  int i = blockIdx.x*256 + threadIdx.x;
  const float* s; u16* d; int idx;
  if (i < n0){ s = s0; d = d0; idx = i; }
  else if (i < n0 + n1){ s = s1; d = d1; idx = i - n0; }
  else if (i < n0 + n1 + n2){ s = s2; d = d2; idx = i - n0 - n1; }
  else return;
  float4 v = ((const float4*)s)[idx];
  us4 o; o.x = f2b(v.x); o.y = f2b(v.y); o.z = f2b(v.z); o.w = f2b(v.w);
  *(us4*)(d + (size_t)idx*4) = o;
}

// ---------------- base_feat [B][C][LQ] -> Xb bf16 [B][LQ][C] ----------------
__global__ __launch_bounds__(256) void k_transpose_x(const float* __restrict__ base, u16* __restrict__ Xb){
  __shared__ float t[32][33];
  int l0 = blockIdx.x*32, c0 = blockIdx.y*32, b = blockIdx.z;
  int tx = threadIdx.x & 31, ty = threadIdx.x >> 5;
  const float* src = base + ((size_t)b*C_ + c0)*LQ + l0;
  #pragma unroll
  for (int i=0;i<4;i++){ int cc = ty + i*8; t[cc][tx] = src[(size_t)cc*LQ + tx]; }
  __syncthreads();
  u16* dst = Xb + ((size_t)b*LQ + l0)*C_ + c0;
  #pragma unroll
  for (int i=0;i<4;i++){ int ll = ty + i*8; dst[(size_t)ll*C_ + tx] = f2b(t[tx][ll]); }
}

// ---------------- support + pe -> smat DENSE [b][s][400][C] ----------------
__global__ __launch_bounds__(256) void k_build_smat(const float* __restrict__ sup, u16* __restrict__ kc){
  __shared__ float t[32][33];
  int p0 = blockIdx.x*32, c0 = blockIdx.y*32;
  int s = blockIdx.z / B_, b = blockIdx.z % B_;
  int tx = threadIdx.x & 31, ty = threadIdx.x >> 5;
  const float* src = sup + ((size_t)(b*S_ + s)*C_ + c0)*LK + p0;
  #pragma unroll
  for (int i=0;i<4;i++){
    int cc = ty + i*8;
    int p = p0 + tx;
    int c = c0 + cc;
    float v = 0.f;
    if (p < LK){
      v = src[(size_t)cc*LK + tx];
      float dv = expf(-(float)(c & ~1) * (9.210340371976184f / 1024.f));
      float arg = (float)p * dv;
      v += (c & 1) ? cosf(arg) : sinf(arg);
    }
    t[cc][tx] = v;
  }
  __syncthreads();
  u16* dkc = kc + ((size_t)((b*S_ + s)*400 + p0))*C_ + c0;
  #pragma unroll
  for (int i=0;i<4;i++){
    int pp = ty + i*8;
    if (p0 + pp < 400) dkc[(size_t)pp*C_ + tx] = f2b(t[tx][pp]);
  }
}

// ---------------- shared helpers ----------------
DEVI void stage_half(const u16* P, int64_t ld, u16* dst, int wid, int r8, int s8){
  #pragma unroll
  for (int it=0; it<2; ++it){
    int ck = wid + it*8;                              // 16 chunks of 8 rows
    gload16(P + (size_t)(ck*8 + r8)*ld + s8*8, dst + ck*512);
  }
}
DEVI bf16x8 ldsread(const u16* base, int row, int kk, int lane){
  int sl = ((kk<<2) + (lane>>4)) ^ (row & 7);
  return *(const bf16x8*)&base[row*64 + sl*8];
}

// ================= 256x256 bf16 MFMA GEMM (dbuf; A staged early, B mid-compute) =================
// C[M][N] = A[M][K] * B[N][K]^T ; 512 threads, 8 waves 2Mx4N; BK=64.
// Issue schedule per iter t: stage A(t+1) [4 gloads]; vmcnt(4) (in-order retire =>
// tile t's A+B complete, only A(t+1) outstanding); barrier; compute 4 quadrants
// with B(t+1)-lo/-hi staged after quadrants 0/1; barrier. Last iter: vmcnt(0).
// CEPI 0: bf16 row-major store (+bias)*scale, n<Nmax, m<Mmax.
// CEPI 1: fp32 transposed store C[n*ldc+m] (+=old unless FIRST);
//         FINAL: out = base*relu(0.2*(old+acc)+Mb[n]).
// swz: 0 none; 1 generic XCD-contig (gx%8==0); 2 PV mapping (grid.x==64, tilesM=16).
template<int CEPI, bool FIRST, bool FINAL, bool BIAS>
__global__ __launch_bounds__(512,1) void k8(
    const u16* __restrict__ A, const u16* __restrict__ Bm, void* __restrict__ Cm,
    const float* __restrict__ bias, const float* __restrict__ basep, const float* __restrict__ Mb,
    int tilesM, int64_t lda, int64_t ldb, int64_t ldc, int NT,
    int bdiv, int64_t aS0, int64_t aS1, int64_t bS0, int64_t bS1,
    int64_t cS0, int64_t cS1, int64_t aZ, int64_t bZ, int64_t cZ,
    int biasS0, float scale, int Nmax, int Mmax, int swz){
  __shared__ __align__(16) u16 lds[2][2][16384];
  int tid = threadIdx.x, lane = tid & 63, wid = tid >> 6;
  int bx = blockIdx.x;
  int mt, ntile;
  if (swz == 2){ int x = bx & 7, j = bx >> 3; mt = 2*x + (j >> 2); ntile = j & 3; }
  else {
    if (swz == 1) bx = (bx & 7) * (gridDim.x >> 3) + (bx >> 3);
    mt = bx % tilesM; ntile = bx / tilesM;
  }
  int z = blockIdx.y, i0 = z / bdiv, i1 = z % bdiv;
  int iz = blockIdx.z;
  const u16* Ab = A + i0*aS0 + i1*aS1 + iz*aZ + (size_t)mt*256*lda;
  const u16* Bb = Bm + i0*bS0 + i1*bS1 + iz*bZ + (size_t)ntile*256*ldb;
  int r8 = lane >> 3, s8 = (lane & 7) ^ r8;
  int wr = wid >> 2, wc = wid & 3;

  f32x4 acc[8][4];
  #pragma unroll
  for (int i=0;i<8;i++)
    #pragma unroll
    for (int j=0;j<4;j++) acc[i][j] = (f32x4){0.f,0.f,0.f,0.f};

  // prologue: stage tile 0 (A then B) into buf 0
  const u16 *ApS = Ab, *BpS = Bb;
  stage_half(ApS,                   lda, &lds[0][0][0],    wid, r8, s8);
  stage_half(ApS + (size_t)128*lda, lda, &lds[0][0][8192], wid, r8, s8);
  stage_half(BpS,                   ldb, &lds[0][1][0],    wid, r8, s8);
  stage_half(BpS + (size_t)128*ldb, ldb, &lds[0][1][8192], wid, r8, s8);
  ApS += 64; BpS += 64;

  for (int t = 0; t < NT; ++t){
    int cur = t & 1, nxt = cur ^ 1;
    bool pf = (t + 1 < NT);
    const u16* lA = &lds[cur][0][0];
    const u16* lB = &lds[cur][1][0];
    u16* sA = &lds[nxt][0][0];
    u16* sB = &lds[nxt][1][0];
    if (pf){
      // stage A(t+1) early: A stream has >= 1 full iteration of latency slack
      stage_half(ApS,                   lda, sA,        wid, r8, s8);
      stage_half(ApS + (size_t)128*lda, lda, sA + 8192, wid, r8, s8);
      asm volatile("s_waitcnt vmcnt(4)" ::: "memory");   // tile t (A+B) complete; A(t+1) in flight
    } else {
      asm volatile("s_waitcnt vmcnt(0)" ::: "memory");
    }
    asm volatile("s_barrier" ::: "memory");

    bf16x8 bfr[4][2];
    #pragma unroll
    for (int jn=0;jn<4;jn++)
      #pragma unroll
      for (int kk=0;kk<2;kk++)
        bfr[jn][kk] = ldsread(lB, wc*64 + jn*16 + (lane & 15), kk, lane);

    #pragma unroll
    for (int p = 0; p < 4; ++p){
      bf16x8 af[2][2];
      #pragma unroll
      for (int dm=0;dm<2;dm++)
        #pragma unroll
        for (int kk=0;kk<2;kk++)
          af[dm][kk] = ldsread(lA, wr*128 + (p*2+dm)*16 + (lane & 15), kk, lane);
      __builtin_amdgcn_s_setprio(1);
      #pragma unroll
      for (int dm=0;dm<2;dm++)
        #pragma unroll
        for (int jn=0;jn<4;jn++)
          #pragma unroll
          for (int kk=0;kk<2;kk++)
            acc[p*2+dm][jn] = __builtin_amdgcn_mfma_f32_16x16x32_bf16(af[dm][kk], bfr[jn][kk], acc[p*2+dm][jn], 0,0,0);
      __builtin_amdgcn_s_setprio(0);
      // stage B(t+1) halves mid-compute (B stream is L2-resident; ~half-iter slack)
      if (p == 0 && pf) stage_half(BpS,                   ldb, sB,        wid, r8, s8);
      if (p == 1 && pf) stage_half(BpS + (size_t)128*ldb, ldb, sB + 8192, wid, r8, s8);
    }
    asm volatile("s_barrier" ::: "memory");
    if (pf){ ApS += 64; BpS += 64; }
  }

  int g = lane >> 4, c16 = lane & 15;
  if constexpr (CEPI == 0){
    u16* Cb = (u16*)Cm + i0*cS0 + i1*cS1 + iz*cZ;
    #pragma unroll
    for (int jn=0;jn<4;jn++){
      int n = ntile*256 + wc*64 + jn*16 + c16;
      if (n >= Nmax) continue;
      float bv = 0.f;
      if (BIAS) bv = bias[(size_t)i0*biasS0 + n];
      #pragma unroll
      for (int im=0;im<8;im++){
        int m = mt*256 + wr*128 + im*16 + g*4;
        if (m >= Mmax) continue;
        #pragma unroll
        for (int r=0;r<4;r++)
          Cb[(size_t)(m + r)*ldc + n] = f2b((acc[im][jn][r] + bv)*scale);
      }
    }
  } else {
    float* Cb = (float*)Cm + i0*cS0 + i1*cS1 + iz*cZ;
    const float* Bs = basep + i0*cS0 + i1*cS1 + iz*cZ;
    #pragma unroll
    for (int jn=0;jn<4;jn++){
      int n = ntile*256 + wc*64 + jn*16 + c16;
      float mbv = 0.f;
      if (FINAL) mbv = Mb[n];
      #pragma unroll
      for (int im=0;im<8;im++){
        int m = mt*256 + wr*128 + im*16 + g*4;
        float* p = Cb + (size_t)n*ldc + m;
        float4 v;
        v.x = acc[im][jn][0]; v.y = acc[im][jn][1]; v.z = acc[im][jn][2]; v.w = acc[im][jn][3];
        if (!FIRST){
          float4 old = *(const float4*)p;
          v.x += old.x; v.y += old.y; v.z += old.z; v.w += old.w;
        }
        if (FINAL){
          float4 bs = *(const float4*)(Bs + (size_t)n*ldc + m);
          v.x = bs.x * fmaxf(0.2f*v.x + mbv, 0.f);
          v.y = bs.y * fmaxf(0.2f*v.y + mbv, 0.f);
          v.z = bs.z * fmaxf(0.2f*v.z + mbv, 0.f);
          v.w = bs.w * fmaxf(0.2f*v.w + mbv, 0.f);
        }
        *(float4*)p = v;
      }
    }
  }
}

// ================= fused QK^T + softmax -> attn[b][l][zz*400..] (dense kv layout) =================
// Known-good structure: 128 q-rows/block, 8 waves x 16 rows, acc[25],
// ALL indices compile-time (rule #20). K layout now [h][b][2000][D] dense.
__global__ __launch_bounds__(512) void k_scores(
    const u16* __restrict__ qws, const u16* __restrict__ kws,
    u16* __restrict__ attn, int h0, int KVP, int padw, int nz){
  __shared__ __align__(16) u16 lQ[128*64];
  __shared__ __align__(16) u16 lK[400*64];
  int tid = threadIdx.x, lane = tid & 63, wid = tid >> 6;
  int m0 = blockIdx.x * 128;
  int b = blockIdx.y;
  int zz = blockIdx.z;
  int s = zz % 5, h = h0 + zz / 5;
  const u16* Qp = qws + ((size_t)(h*B_ + b)*LQ + m0)*D_;
  const u16* Kp = kws + ((size_t)((h*B_ + b)*2000 + s*400))*D_;
  int r8 = lane >> 3, s8 = (lane & 7) ^ r8;
  f32x4 acc[25];
  #pragma unroll
  for (int t=0;t<25;t++) acc[t] = (f32x4){0.f,0.f,0.f,0.f};
  int wm = wid * 16;
  for (int k0 = 0; k0 < 256; k0 += 64){
    __syncthreads();
    #pragma unroll
    for (int c = 0; c < 2; ++c){
      int cc = wid + c*8;
      int row = cc*8 + r8;
      gload16(Qp + (size_t)row*D_ + k0 + s8*8, &lQ[cc*512]);
    }
    for (int cc = wid; cc < 50; cc += 8){
      int row = cc*8 + r8;
      gload16(Kp + (size_t)row*D_ + k0 + s8*8, &lK[cc*512]);
    }
    __syncthreads();
    #pragma unroll
    for (int kk = 0; kk < 2; ++kk){
      int rowA = wm + (lane & 15);
      int slA = ((kk<<2) + (lane>>4)) ^ (rowA & 7);
      bf16x8 af = *(const bf16x8*)&lQ[rowA*64 + slA*8];
      #pragma unroll
      for (int t=0;t<25;t++){
        int rowB = t*16 + (lane & 15);
        int slB = ((kk<<2) + (lane>>4)) ^ (rowB & 7);
        bf16x8 bf = *(const bf16x8*)&lK[rowB*64 + slB*8];
        acc[t] = __builtin_amdgcn_mfma_f32_16x16x32_bf16(af, bf, acc[t], 0,0,0);
      }
    }
  }
  float mx[4] = {-1e30f,-1e30f,-1e30f,-1e30f};
  #pragma unroll
  for (int t=0;t<25;t++)
    #pragma unroll
    for (int r=0;r<4;r++) mx[r] = fmaxf(mx[r], acc[t][r]);
  #pragma unroll
  for (int r=0;r<4;r++){
    mx[r] = fmaxf(mx[r], __shfl_xor(mx[r], 1));
    mx[r] = fmaxf(mx[r], __shfl_xor(mx[r], 2));
    mx[r] = fmaxf(mx[r], __shfl_xor(mx[r], 4));
    mx[r] = fmaxf(mx[r], __shfl_xor(mx[r], 8));
  }
  float sm[4] = {0.f,0.f,0.f,0.f};
  #pragma unroll
  for (int t=0;t<25;t++)
    #pragma unroll
    for (int r=0;r<4;r++){ float e = __expf(acc[t][r] - mx[r]); acc[t][r] = e; sm[r] += e; }
  #pragma unroll
  for (int r=0;r<4;r++){
    sm[r] += __shfl_xor(sm[r], 1);
    sm[r] += __shfl_xor(sm[r], 2);
    sm[r] += __shfl_xor(sm[r], 4);
    sm[r] += __shfl_xor(sm[r], 8);
    sm[r] = 1.f / sm[r];
  }
  u16* ap = attn + ((size_t)b*LQ + m0 + wm)*KVP + (size_t)zz*400;
  int g = lane >> 4, c16 = lane & 15;
  #pragma unroll
  for (int t=0;t<25;t++)
    #pragma unroll
    for (int r=0;r<4;r++)
      ap[(size_t)(g*4 + r)*KVP + t*16 + c16] = f2b(acc[t][r] * sm[r]);
  if (zz == nz - 1 && padw > 0){
    u16* base2 = attn + ((size_t)b*LQ + m0)*KVP + (KVP - padw);
    int total = 128 * padw;
    for (int i = tid; i < total; i += 512){
      int rr = i / padw, cc = i % padw;
      base2[(size_t)rr*KVP + cc] = 0;
    }
  }
}

extern "C" void kernel_launch(void* const* d_in, const int* in_sizes, int n_in,
                              void* d_out, int out_size, void* d_ws, size_t ws_size,
                              hipStream_t stream){
  const float* base = (const float*)d_in[0];
  const float* sup  = (const float*)d_in[1];
  const float* Qw   = (const float*)d_in[2];
  const float* Qb   = (const float*)d_in[3];
  const float* Kw   = (const float*)d_in[4];
  const float* Kb   = (const float*)d_in[5];
  const float* Mw   = (const float*)d_in[6];
  const float* Mb   = (const float*)d_in[7];
  float* out = (float*)d_out;
  char* ws = (char*)d_ws;

  const int GH = (ws_size >= 247988224ull) ? 2 : 1;   // heads per group
  const int NG = H_ / GH;
  const int NZ = GH * 5;
  const int KVP = (NZ*400 + 63) & ~63;                // 4032 (GH=2) / 2048 (GH=1)
  const int NT = KVP / 64;
  const int PADW = KVP - NZ*400;

  u16* wQw = (u16*)(ws + 0);            //  2,097,152  [H][D][C]
  u16* wKw = (u16*)(ws + 2097152);      //  2,097,152  [H][D][C]
  u16* wMw = (u16*)(ws + 4194304);      //  8,388,608  [C][H*C]
  u16* wKC = (u16*)(ws + 12582912);     // 16,384,000 used (slot 18,350,080)  smat [B][S][400][C] dense
  u16* wK  = (u16*)(ws + 30932992);     // 16,384,000 used (slot 18,350,080)  k [H][B][2000][D] dense
  u16* wQ  = (u16*)(ws + 49283072);     // 33,554,432  q [H][B][LQ][D]
  u16* wVt = (u16*)(ws + 82837504);     // B*C*KVP*2   Vt [B][C][KVP]
  u16* wAT = (u16*)(ws + 82837504 + (size_t)B_*C_*KVP*2);  // B*LQ*KVP*2  attn [B][LQ][KVP]
  u16* wXb = wAT;                       // Xb [B][LQ][C] aliases attn (dead after q-proj)

  const int BIG = 1 << 30;

  k_cvt3<<<6144, 256, 0, stream>>>(Qw, wQw, 262144, Kw, wKw, 262144, Mw, wMw, 1048576);
  k_transpose_x<<<dim3(128, 32, 4), 256, 0, stream>>>(base, wXb);
  k_build_smat<<<dim3(13, 32, 20), 256, 0, stream>>>(sup, wKC);

  // k-proj (dense): k[h][b][s*400+j] = smat[b][s-concat] @ Kw[h]^T + Kb
  // M = 2000 (8 tiles of 256, Mmax=2000), N=256, K=1024; grid (8, 16): i0=h, i1=b.
  k8<0,false,false,true><<<dim3(8, 16, 1), 512, 0, stream>>>(
      wKC, wKw, wK, Kb, nullptr, nullptr,
      8, C_, C_, D_, 16,
      4, 0, (int64_t)S_*400*C_, (int64_t)D_*C_, 0,
      (int64_t)B_*2000*D_, (int64_t)2000*D_, 0, 0, 0,
      D_, 1.f, BIG, 2000, 0);

  // q-proj: q[h][b] = (Xb[b] @ Qw[h]^T + Qb)/16      (M=4096, N=256, K=1024)
  k8<0,false,false,true><<<dim3(16, 16, 1), 512, 0, stream>>>(
      wXb, wQw, wQ, Qb, nullptr, nullptr,
      16, C_, C_, D_, 16,
      4, 0, (int64_t)LQ*C_, (int64_t)D_*C_, 0,
      (int64_t)B_*LQ*D_, (int64_t)LQ*D_, 0, 0, 0,
      D_, 1.f/16.f, BIG, BIG, 1);

  for (int g = 0; g < NG; ++g){
    // Vt (dense): Vt[b][c][hh*2000 + n] = sum_c' Mw[c][(g*GH+hh)*C+c'] * smat[b][n-dense][c']
    // M=1024 (4 mt), N=2000 (8 ntiles, Nmax=2000), K=1024; grid (32, GH, 4): i0=hh, iz=b.
    k8<0,false,false,false><<<dim3(32, GH, 4), 512, 0, stream>>>(
        wMw + (size_t)(g*GH)*C_, wKC, wVt, nullptr, nullptr, nullptr,
        4, (int64_t)H_*C_, C_, KVP, 16,
        1, (int64_t)C_, 0, 0, 0,
        2000, 0, 0, (int64_t)S_*400*C_, (int64_t)C_*KVP,
        0, 1.f, 2000, BIG, 0);

    // scores+softmax (dense kv layout)
    k_scores<<<dim3(32, 4, NZ), 512, 0, stream>>>(wQ, wK, wAT, g*GH, KVP, PADW, NZ);

    // PV: out[b][c][l] (+)= attn[b][l][:] . Vt[b][c][:]   (M=4096, N=1024, K=KVP)
    // grid (64, 4): swz=2 puts all 4 nt of an mt-pair on one XCD (L2 attn reuse).
    if (g == 0 && NG > 1){
      k8<1,true,false,false><<<dim3(64, 4, 1), 512, 0, stream>>>(
          wAT, wVt, out, nullptr, base, Mb,
          16, KVP, KVP, LQ, NT,
          1, (int64_t)LQ*KVP, 0, (int64_t)C_*KVP, 0,
          (int64_t)C_*LQ, 0, 0, 0, 0,
          0, 1.f, BIG, BIG, 2);
    } else if (g == NG - 1){
      k8<1,false,true,false><<<dim3(64, 4, 1), 512, 0, stream>>>(
          wAT, wVt, out, nullptr, base, Mb,
          16, KVP, KVP, LQ, NT,
          1, (int64_t)LQ*KVP, 0, (int64_t)C_*KVP, 0,
          (int64_t)C_*LQ, 0, 0, 0, 0,
          0, 1.f, BIG, BIG, 2);
    } else {
      k8<1,false,false,false><<<dim3(64, 4, 1), 512, 0, stream>>>(
          wAT, wVt, out, nullptr, base, Mb,
          16, KVP, KVP, LQ, NT,
          1, (int64_t)LQ*KVP, 0, (int64_t)C_*KVP, 0,
          (int64_t)C_*LQ, 0, 0, 0, 0,
          0, 1.f, BIG, BIG, 2);
    }
  }
}

// Round 15
// 633.275 us; speedup vs baseline: 1.2369x; 1.0442x over previous
//
#include <hip/hip_runtime.h>
#include <stdint.h>

#define DEVI __device__ __forceinline__

typedef __attribute__((ext_vector_type(8))) short bf16x8;
typedef __attribute__((ext_vector_type(4))) float f32x4;
typedef __attribute__((ext_vector_type(4))) unsigned short us4;
typedef unsigned short u16;

constexpr int B_ = 4, S_ = 5, H_ = 4, C_ = 1024, D_ = 256;
constexpr int LQ = 4096, LK = 400;

DEVI u16 f2b(float f){
  uint32_t x = __float_as_uint(f);
  uint32_t r = (x + 0x7FFFu + ((x >> 16) & 1u)) >> 16;
  return (u16)r;
}

typedef __attribute__((address_space(1))) const void ASG;
typedef __attribute__((address_space(3))) void ASL;
DEVI void gload16(const void* g, void* l){
  __builtin_amdgcn_global_load_lds((ASG*)g, (ASL*)l, 16, 0, 0);
}

// ---------------- fp32 -> bf16 convert (3 arrays, one launch) ----------------
__global__ __launch_bounds__(256) void k_cvt3(
    const float* __restrict__ s0, u16* __restrict__ d0, int n0,
    const float* __restrict__ s1, u16* __restrict__ d1, int n1,
    const float* __restrict__ s2, u16* __restrict__ d2, int n2){
  int i = blockIdx.x*256 + threadIdx.x;
  const float* s; u16* d; int idx;
  if (i < n0){ s = s0; d = d0; idx = i; }
  else if (i < n0 + n1){ s = s1; d = d1; idx = i - n0; }
  else if (i < n0 + n1 + n2){ s = s2; d = d2; idx = i - n0 - n1; }
  else return;
  float4 v = ((const float4*)s)[idx];
  us4 o; o.x = f2b(v.x); o.y = f2b(v.y); o.z = f2b(v.z); o.w = f2b(v.w);
  *(us4*)(d + (size_t)idx*4) = o;
}

// ---------------- base_feat [B][C][LQ] -> Xb bf16 [B][LQ][C] ----------------
__global__ __launch_bounds__(256) void k_transpose_x(const float* __restrict__ base, u16* __restrict__ Xb){
  __shared__ float t[32][33];
  int l0 = blockIdx.x*32, c0 = blockIdx.y*32, b = blockIdx.z;
  int tx = threadIdx.x & 31, ty = threadIdx.x >> 5;
  const float* src = base + ((size_t)b*C_ + c0)*LQ + l0;
  #pragma unroll
  for (int i=0;i<4;i++){ int cc = ty + i*8; t[cc][tx] = src[(size_t)cc*LQ + tx]; }
  __syncthreads();
  u16* dst = Xb + ((size_t)b*LQ + l0)*C_ + c0;
  #pragma unroll
  for (int i=0;i<4;i++){ int ll = ty + i*8; dst[(size_t)ll*C_ + tx] = f2b(t[tx][ll]); }
}

// ---------------- support + pe -> smat DENSE [b][s][400][C] ----------------
__global__ __launch_bounds__(256) void k_build_smat(const float* __restrict__ sup, u16* __restrict__ kc){
  __shared__ float t[32][33];
  int p0 = blockIdx.x*32, c0 = blockIdx.y*32;
  int s = blockIdx.z / B_, b = blockIdx.z % B_;
  int tx = threadIdx.x & 31, ty = threadIdx.x >> 5;
  const float* src = sup + ((size_t)(b*S_ + s)*C_ + c0)*LK + p0;
  #pragma unroll
  for (int i=0;i<4;i++){
    int cc = ty + i*8;
    int p = p0 + tx;
    int c = c0 + cc;
    float v = 0.f;
    if (p < LK){
      v = src[(size_t)cc*LK + tx];
      float dv = expf(-(float)(c & ~1) * (9.210340371976184f / 1024.f));
      float arg = (float)p * dv;
      v += (c & 1) ? cosf(arg) : sinf(arg);
    }
    t[cc][tx] = v;
  }
  __syncthreads();
  u16* dkc = kc + ((size_t)((b*S_ + s)*400 + p0))*C_ + c0;
  #pragma unroll
  for (int i=0;i<4;i++){
    int pp = ty + i*8;
    if (p0 + pp < 400) dkc[(size_t)pp*C_ + tx] = f2b(t[tx][pp]);
  }
}

// ---------------- shared helpers ----------------
DEVI void stage_half(const u16* P, int64_t ld, u16* dst, int wid, int r8, int s8){
  #pragma unroll
  for (int it=0; it<2; ++it){
    int ck = wid + it*8;                              // 16 chunks of 8 rows
    gload16(P + (size_t)(ck*8 + r8)*ld + s8*8, dst + ck*512);
  }
}
DEVI bf16x8 ldsread(const u16* base, int row, int kk, int lane){
  int sl = ((kk<<2) + (lane>>4)) ^ (row & 7);
  return *(const bf16x8*)&base[row*64 + sl*8];
}

// ================= 256x256 bf16 MFMA GEMM (dbuf; A staged early, B mid-compute) =================
// C[M][N] = A[M][K] * B[N][K]^T ; 512 threads, 8 waves 2Mx4N; BK=64.
// CEPI 0: bf16 row-major store (+bias)*scale, n<Nmax, m<Mmax.
// CEPI 1: fp32 transposed store C[n*ldc+m] (+=old unless FIRST);
//         FINAL: out = base*relu(0.2*(old+acc)+Mb[n]).
// swz: 0 none; 1 generic XCD-contig (gx%8==0); 2 PV mapping (grid.x==64, tilesM=16).
template<int CEPI, bool FIRST, bool FINAL, bool BIAS>
__global__ __launch_bounds__(512,1) void k8(
    const u16* __restrict__ A, const u16* __restrict__ Bm, void* __restrict__ Cm,
    const float* __restrict__ bias, const float* __restrict__ basep, const float* __restrict__ Mb,
    int tilesM, int64_t lda, int64_t ldb, int64_t ldc, int NT,
    int bdiv, int64_t aS0, int64_t aS1, int64_t bS0, int64_t bS1,
    int64_t cS0, int64_t cS1, int64_t aZ, int64_t bZ, int64_t cZ,
    int biasS0, float scale, int Nmax, int Mmax, int swz){
  __shared__ __align__(16) u16 lds[2][2][16384];
  int tid = threadIdx.x, lane = tid & 63, wid = tid >> 6;
  int bx = blockIdx.x;
  int mt, ntile;
  if (swz == 2){ int x = bx & 7, j = bx >> 3; mt = 2*x + (j >> 2); ntile = j & 3; }
  else {
    if (swz == 1) bx = (bx & 7) * (gridDim.x >> 3) + (bx >> 3);
    mt = bx % tilesM; ntile = bx / tilesM;
  }
  int z = blockIdx.y, i0 = z / bdiv, i1 = z % bdiv;
  int iz = blockIdx.z;
  const u16* Ab = A + i0*aS0 + i1*aS1 + iz*aZ + (size_t)mt*256*lda;
  const u16* Bb = Bm + i0*bS0 + i1*bS1 + iz*bZ + (size_t)ntile*256*ldb;
  int r8 = lane >> 3, s8 = (lane & 7) ^ r8;
  int wr = wid >> 2, wc = wid & 3;

  f32x4 acc[8][4];
  #pragma unroll
  for (int i=0;i<8;i++)
    #pragma unroll
    for (int j=0;j<4;j++) acc[i][j] = (f32x4){0.f,0.f,0.f,0.f};

  // prologue: stage tile 0 (A then B) into buf 0
  const u16 *ApS = Ab, *BpS = Bb;
  stage_half(ApS,                   lda, &lds[0][0][0],    wid, r8, s8);
  stage_half(ApS + (size_t)128*lda, lda, &lds[0][0][8192], wid, r8, s8);
  stage_half(BpS,                   ldb, &lds[0][1][0],    wid, r8, s8);
  stage_half(BpS + (size_t)128*ldb, ldb, &lds[0][1][8192], wid, r8, s8);
  ApS += 64; BpS += 64;

  for (int t = 0; t < NT; ++t){
    int cur = t & 1, nxt = cur ^ 1;
    bool pf = (t + 1 < NT);
    const u16* lA = &lds[cur][0][0];
    const u16* lB = &lds[cur][1][0];
    u16* sA = &lds[nxt][0][0];
    u16* sB = &lds[nxt][1][0];
    if (pf){
      // stage A(t+1) early: A stream has >= 1 full iteration of latency slack
      stage_half(ApS,                   lda, sA,        wid, r8, s8);
      stage_half(ApS + (size_t)128*lda, lda, sA + 8192, wid, r8, s8);
      asm volatile("s_waitcnt vmcnt(4)" ::: "memory");   // tile t (A+B) complete; A(t+1) in flight
    } else {
      asm volatile("s_waitcnt vmcnt(0)" ::: "memory");
    }
    asm volatile("s_barrier" ::: "memory");

    bf16x8 bfr[4][2];
    #pragma unroll
    for (int jn=0;jn<4;jn++)
      #pragma unroll
      for (int kk=0;kk<2;kk++)
        bfr[jn][kk] = ldsread(lB, wc*64 + jn*16 + (lane & 15), kk, lane);

    #pragma unroll
    for (int p = 0; p < 4; ++p){
      bf16x8 af[2][2];
      #pragma unroll
      for (int dm=0;dm<2;dm++)
        #pragma unroll
        for (int kk=0;kk<2;kk++)
          af[dm][kk] = ldsread(lA, wr*128 + (p*2+dm)*16 + (lane & 15), kk, lane);
      __builtin_amdgcn_s_setprio(1);
      #pragma unroll
      for (int dm=0;dm<2;dm++)
        #pragma unroll
        for (int jn=0;jn<4;jn++)
          #pragma unroll
          for (int kk=0;kk<2;kk++)
            acc[p*2+dm][jn] = __builtin_amdgcn_mfma_f32_16x16x32_bf16(af[dm][kk], bfr[jn][kk], acc[p*2+dm][jn], 0,0,0);
      __builtin_amdgcn_s_setprio(0);
      // stage B(t+1) halves mid-compute (B stream is L2-resident; ~half-iter slack)
      if (p == 0 && pf) stage_half(BpS,                   ldb, sB,        wid, r8, s8);
      if (p == 1 && pf) stage_half(BpS + (size_t)128*ldb, ldb, sB + 8192, wid, r8, s8);
    }
    asm volatile("s_barrier" ::: "memory");
    if (pf){ ApS += 64; BpS += 64; }
  }

  int g = lane >> 4, c16 = lane & 15;
  if constexpr (CEPI == 0){
    u16* Cb = (u16*)Cm + i0*cS0 + i1*cS1 + iz*cZ;
    #pragma unroll
    for (int jn=0;jn<4;jn++){
      int n = ntile*256 + wc*64 + jn*16 + c16;
      if (n >= Nmax) continue;
      float bv = 0.f;
      if (BIAS) bv = bias[(size_t)i0*biasS0 + n];
      #pragma unroll
      for (int im=0;im<8;im++){
        int m = mt*256 + wr*128 + im*16 + g*4;
        if (m >= Mmax) continue;
        #pragma unroll
        for (int r=0;r<4;r++)
          Cb[(size_t)(m + r)*ldc + n] = f2b((acc[im][jn][r] + bv)*scale);
      }
    }
  } else {
    float* Cb = (float*)Cm + i0*cS0 + i1*cS1 + iz*cZ;
    const float* Bs = basep + i0*cS0 + i1*cS1 + iz*cZ;
    #pragma unroll
    for (int jn=0;jn<4;jn++){
      int n = ntile*256 + wc*64 + jn*16 + c16;
      float mbv = 0.f;
      if (FINAL) mbv = Mb[n];
      #pragma unroll
      for (int im=0;im<8;im++){
        int m = mt*256 + wr*128 + im*16 + g*4;
        float* p = Cb + (size_t)n*ldc + m;
        float4 v;
        v.x = acc[im][jn][0]; v.y = acc[im][jn][1]; v.z = acc[im][jn][2]; v.w = acc[im][jn][3];
        if (!FIRST){
          float4 old = *(const float4*)p;
          v.x += old.x; v.y += old.y; v.z += old.z; v.w += old.w;
        }
        if (FINAL){
          float4 bs = *(const float4*)(Bs + (size_t)n*ldc + m);
          v.x = bs.x * fmaxf(0.2f*v.x + mbv, 0.f);
          v.y = bs.y * fmaxf(0.2f*v.y + mbv, 0.f);
          v.z = bs.z * fmaxf(0.2f*v.z + mbv, 0.f);
          v.w = bs.w * fmaxf(0.2f*v.w + mbv, 0.f);
        }
        *(float4*)p = v;
      }
    }
  }
}

// ================= fused QK^T + softmax -> attn[b][l][zz*400..] (dense kv layout) =================
// Known-good wave layout (8 waves x 16 q-rows, acc[25], all indices compile-time),
// now with k8-style double-buffered staging + counted vmcnt:
// stage k0(t+1) into buf^1 at iter top (9 loads/wave: 2 Q + 7 K uniform, K staged
// 448 rows -- rows 400..447 belong to next s, compute-ignored, bounds-audited);
// vmcnt(9) waits tile t only; two barriers per iter (same protocol as k8).
__global__ __launch_bounds__(512,1) void k_scores(
    const u16* __restrict__ qws, const u16* __restrict__ kws,
    u16* __restrict__ attn, int h0, int KVP, int padw, int nz){
  __shared__ __align__(16) u16 lQ[2][128*64];
  __shared__ __align__(16) u16 lK[2][448*64];
  int tid = threadIdx.x, lane = tid & 63, wid = tid >> 6;
  int m0 = blockIdx.x * 128;
  int b = blockIdx.y;
  int zz = blockIdx.z;
  int s = zz % 5, h = h0 + zz / 5;
  const u16* Qp = qws + ((size_t)(h*B_ + b)*LQ + m0)*D_;
  const u16* Kp = kws + ((size_t)((h*B_ + b)*2000 + s*400))*D_;
  int r8 = lane >> 3, s8 = (lane & 7) ^ r8;
  f32x4 acc[25];
  #pragma unroll
  for (int t=0;t<25;t++) acc[t] = (f32x4){0.f,0.f,0.f,0.f};
  int wm = wid * 16;

  // prologue: stage k0=0 into buf 0 (9 loads/wave)
  #pragma unroll
  for (int c = 0; c < 2; ++c){
    int cc = wid + c*8;
    gload16(Qp + (size_t)(cc*8 + r8)*D_ + s8*8, &lQ[0][cc*512]);
  }
  #pragma unroll
  for (int i = 0; i < 7; ++i){
    int ck = wid + i*8;
    gload16(Kp + (size_t)(ck*8 + r8)*D_ + s8*8, &lK[0][ck*512]);
  }

  for (int t = 0; t < 4; ++t){
    if (t < 3){
      int k1 = (t+1)*64;
      int nb = (t+1) & 1;
      #pragma unroll
      for (int c = 0; c < 2; ++c){
        int cc = wid + c*8;
        gload16(Qp + (size_t)(cc*8 + r8)*D_ + k1 + s8*8, &lQ[nb][cc*512]);
      }
      #pragma unroll
      for (int i = 0; i < 7; ++i){
        int ck = wid + i*8;
        gload16(Kp + (size_t)(ck*8 + r8)*D_ + k1 + s8*8, &lK[nb][ck*512]);
      }
      asm volatile("s_waitcnt vmcnt(9)" ::: "memory");   // tile t complete; t+1 in flight
    } else {
      asm volatile("s_waitcnt vmcnt(0)" ::: "memory");
    }
    asm volatile("s_barrier" ::: "memory");
    const u16* lq = &lQ[t & 1][0];
    const u16* lk = &lK[t & 1][0];
    #pragma unroll
    for (int kk = 0; kk < 2; ++kk){
      int rowA = wm + (lane & 15);
      int slA = ((kk<<2) + (lane>>4)) ^ (rowA & 7);
      bf16x8 af = *(const bf16x8*)&lq[rowA*64 + slA*8];
      #pragma unroll
      for (int tt=0;tt<25;tt++){
        int rowB = tt*16 + (lane & 15);
        int slB = ((kk<<2) + (lane>>4)) ^ (rowB & 7);
        bf16x8 bf = *(const bf16x8*)&lk[rowB*64 + slB*8];
        acc[tt] = __builtin_amdgcn_mfma_f32_16x16x32_bf16(af, bf, acc[tt], 0,0,0);
      }
    }
    asm volatile("s_barrier" ::: "memory");   // all reads of buf[t&1] done before next stage
  }

  float mx[4] = {-1e30f,-1e30f,-1e30f,-1e30f};
  #pragma unroll
  for (int t=0;t<25;t++)
    #pragma unroll
    for (int r=0;r<4;r++) mx[r] = fmaxf(mx[r], acc[t][r]);
  #pragma unroll
  for (int r=0;r<4;r++){
    mx[r] = fmaxf(mx[r], __shfl_xor(mx[r], 1));
    mx[r] = fmaxf(mx[r], __shfl_xor(mx[r], 2));
    mx[r] = fmaxf(mx[r], __shfl_xor(mx[r], 4));
    mx[r] = fmaxf(mx[r], __shfl_xor(mx[r], 8));
  }
  float sm[4] = {0.f,0.f,0.f,0.f};
  #pragma unroll
  for (int t=0;t<25;t++)
    #pragma unroll
    for (int r=0;r<4;r++){ float e = __expf(acc[t][r] - mx[r]); acc[t][r] = e; sm[r] += e; }
  #pragma unroll
  for (int r=0;r<4;r++){
    sm[r] += __shfl_xor(sm[r], 1);
    sm[r] += __shfl_xor(sm[r], 2);
    sm[r] += __shfl_xor(sm[r], 4);
    sm[r] += __shfl_xor(sm[r], 8);
    sm[r] = 1.f / sm[r];
  }
  u16* ap = attn + ((size_t)b*LQ + m0 + wm)*KVP + (size_t)zz*400;
  int g = lane >> 4, c16 = lane & 15;
  #pragma unroll
  for (int t=0;t<25;t++)
    #pragma unroll
    for (int r=0;r<4;r++)
      ap[(size_t)(g*4 + r)*KVP + t*16 + c16] = f2b(acc[t][r] * sm[r]);
  if (zz == nz - 1 && padw > 0){
    u16* base2 = attn + ((size_t)b*LQ + m0)*KVP + (KVP - padw);
    int total = 128 * padw;
    for (int i = tid; i < total; i += 512){
      int rr = i / padw, cc = i % padw;
      base2[(size_t)rr*KVP + cc] = 0;
    }
  }
}

extern "C" void kernel_launch(void* const* d_in, const int* in_sizes, int n_in,
                              void* d_out, int out_size, void* d_ws, size_t ws_size,
                              hipStream_t stream){
  const float* base = (const float*)d_in[0];
  const float* sup  = (const float*)d_in[1];
  const float* Qw   = (const float*)d_in[2];
  const float* Qb   = (const float*)d_in[3];
  const float* Kw   = (const float*)d_in[4];
  const float* Kb   = (const float*)d_in[5];
  const float* Mw   = (const float*)d_in[6];
  const float* Mb   = (const float*)d_in[7];
  float* out = (float*)d_out;
  char* ws = (char*)d_ws;

  const int GH = (ws_size >= 247988224ull) ? 2 : 1;   // heads per group
  const int NG = H_ / GH;
  const int NZ = GH * 5;
  const int KVP = (NZ*400 + 63) & ~63;                // 4032 (GH=2) / 2048 (GH=1)
  const int NT = KVP / 64;
  const int PADW = KVP - NZ*400;

  u16* wQw = (u16*)(ws + 0);            //  2,097,152  [H][D][C]
  u16* wKw = (u16*)(ws + 2097152);      //  2,097,152  [H][D][C]
  u16* wMw = (u16*)(ws + 4194304);      //  8,388,608  [C][H*C]
  u16* wKC = (u16*)(ws + 12582912);     // 16,384,000 used (slot 18,350,080)  smat [B][S][400][C] dense
  u16* wK  = (u16*)(ws + 30932992);     // 16,384,000 used (slot 18,350,080)  k [H][B][2000][D] dense
  u16* wQ  = (u16*)(ws + 49283072);     // 33,554,432  q [H][B][LQ][D]
  u16* wVt = (u16*)(ws + 82837504);     // B*C*KVP*2   Vt [B][C][KVP]
  u16* wAT = (u16*)(ws + 82837504 + (size_t)B_*C_*KVP*2);  // B*LQ*KVP*2  attn [B][LQ][KVP]
  u16* wXb = wAT;                       // Xb [B][LQ][C] aliases attn (dead after q-proj)

  const int BIG = 1 << 30;

  k_cvt3<<<6144, 256, 0, stream>>>(Qw, wQw, 262144, Kw, wKw, 262144, Mw, wMw, 1048576);
  k_transpose_x<<<dim3(128, 32, 4), 256, 0, stream>>>(base, wXb);
  k_build_smat<<<dim3(13, 32, 20), 256, 0, stream>>>(sup, wKC);

  // k-proj (dense): k[h][b][s*400+j] = smat[b][s-concat] @ Kw[h]^T + Kb
  // M = 2000 (8 tiles of 256, Mmax=2000), N=256, K=1024; grid (8, 16): i0=h, i1=b.
  k8<0,false,false,true><<<dim3(8, 16, 1), 512, 0, stream>>>(
      wKC, wKw, wK, Kb, nullptr, nullptr,
      8, C_, C_, D_, 16,
      4, 0, (int64_t)S_*400*C_, (int64_t)D_*C_, 0,
      (int64_t)B_*2000*D_, (int64_t)2000*D_, 0, 0, 0,
      D_, 1.f, BIG, 2000, 0);

  // q-proj: q[h][b] = (Xb[b] @ Qw[h]^T + Qb)/16      (M=4096, N=256, K=1024)
  k8<0,false,false,true><<<dim3(16, 16, 1), 512, 0, stream>>>(
      wXb, wQw, wQ, Qb, nullptr, nullptr,
      16, C_, C_, D_, 16,
      4, 0, (int64_t)LQ*C_, (int64_t)D_*C_, 0,
      (int64_t)B_*LQ*D_, (int64_t)LQ*D_, 0, 0, 0,
      D_, 1.f/16.f, BIG, BIG, 1);

  for (int g = 0; g < NG; ++g){
    // Vt (dense): Vt[b][c][hh*2000 + n] = sum_c' Mw[c][(g*GH+hh)*C+c'] * smat[b][n-dense][c']
    // M=1024 (4 mt), N=2000 (8 ntiles, Nmax=2000), K=1024; grid (32, GH, 4): i0=hh, iz=b.
    k8<0,false,false,false><<<dim3(32, GH, 4), 512, 0, stream>>>(
        wMw + (size_t)(g*GH)*C_, wKC, wVt, nullptr, nullptr, nullptr,
        4, (int64_t)H_*C_, C_, KVP, 16,
        1, (int64_t)C_, 0, 0, 0,
        2000, 0, 0, (int64_t)S_*400*C_, (int64_t)C_*KVP,
        0, 1.f, 2000, BIG, 0);

    // scores+softmax (dense kv layout, dbuf staging)
    k_scores<<<dim3(32, 4, NZ), 512, 0, stream>>>(wQ, wK, wAT, g*GH, KVP, PADW, NZ);

    // PV: out[b][c][l] (+)= attn[b][l][:] . Vt[b][c][:]   (M=4096, N=1024, K=KVP)
    // grid (64, 4): swz=2 puts all 4 nt of an mt-pair on one XCD (L2 attn reuse).
    if (g == 0 && NG > 1){
      k8<1,true,false,false><<<dim3(64, 4, 1), 512, 0, stream>>>(
          wAT, wVt, out, nullptr, base, Mb,
          16, KVP, KVP, LQ, NT,
          1, (int64_t)LQ*KVP, 0, (int64_t)C_*KVP, 0,
          (int64_t)C_*LQ, 0, 0, 0, 0,
          0, 1.f, BIG, BIG, 2);
    } else if (g == NG - 1){
      k8<1,false,true,false><<<dim3(64, 4, 1), 512, 0, stream>>>(
          wAT, wVt, out, nullptr, base, Mb,
          16, KVP, KVP, LQ, NT,
          1, (int64_t)LQ*KVP, 0, (int64_t)C_*KVP, 0,
          (int64_t)C_*LQ, 0, 0, 0, 0,
          0, 1.f, BIG, BIG, 2);
    } else {
      k8<1,false,false,false><<<dim3(64, 4, 1), 512, 0, stream>>>(
          wAT, wVt, out, nullptr, base, Mb,
          16, KVP, KVP, LQ, NT,
          1, (int64_t)LQ*KVP, 0, (int64_t)C_*KVP, 0,
          (int64_t)C_*LQ, 0, 0, 0, 0,
          0, 1.f, BIG, BIG, 2);
    }
  }
}